// Round 5
// baseline (147.844 us; speedup 1.0000x reference)
//
#include <hip/hip_runtime.h>
#include <hip/hip_bf16.h>

// VQ-VAE quantization forward for MI355X (gfx950).
// outputs (concat in d_out, fp32): quantized_ [16*4096*256], commitment_loss [1], perplexity [1]
//
// R5: 1024 blocks x 128 threads (2 waves); wave owns 32 rows (two resident A-frag sets)
// so each B ds_read_b128 feeds 2 MFMAs (halves LDS traffic/CU). 32KB codebook stages
// (8 stages of 64 codes) -> ~37KB LDS -> 4 blocks/CU for cross-block phase overlap.

typedef _Float16 half8_t __attribute__((ext_vector_type(8)));
typedef _Float16 half4_t __attribute__((ext_vector_type(4)));
typedef float f32x4 __attribute__((ext_vector_type(4)));

static constexpr int kRows = 65536;   // N*T
static constexpr int kD = 256;
static constexpr int kM = 512;
static constexpr int kBM = 64;        // rows per block

typedef const unsigned int __attribute__((address_space(1)))* gas_t;
typedef unsigned int __attribute__((address_space(3)))* las_t;

// ---------------- prep: normalize codebook -> fp16 in MFMA B-fragment order, bias, zero hist/loss --------
// swz layout (halves): [group g=c>>4][ko=k>>5][lane = qd*16 + (c&15)][j = k&7], qd=(k>>3)&3.
// A wave's read at lane*16B yields B[k=ko*32+qd*8+j][n=g*16+ln] as mfma_f32_16x16x32_f16 wants.
__global__ void vq_prep(const float* __restrict__ emb, _Float16* __restrict__ swz,
                        float* __restrict__ bias, unsigned int* __restrict__ hist,
                        float* __restrict__ loss) {
    const int j = blockIdx.x;       // code row, 512 blocks
    const int lane = threadIdx.x;   // 64 threads = 1 wave
    float4 v = ((const float4*)(emb + j * kD))[lane];
    float ss = v.x * v.x + v.y * v.y + v.z * v.z + v.w * v.w;
    #pragma unroll
    for (int off = 32; off > 0; off >>= 1) ss += __shfl_xor(ss, off);
    const float scale = 1.0f / (sqrtf(ss) + 1e-4f);
    if (lane == 0) bias[j] = 0.5f * ss * scale * scale;
    half4_t h;
    h[0] = (_Float16)(v.x * scale);
    h[1] = (_Float16)(v.y * scale);
    h[2] = (_Float16)(v.z * scale);
    h[3] = (_Float16)(v.w * scale);
    const int k0 = lane * 4;        // this lane covers k0..k0+3 (within one 8-half j-chunk)
    const int ko = k0 >> 5;
    const int qd = (k0 >> 3) & 3;
    const int jj = k0 & 7;          // 0 or 4
    const int off_h = (j >> 4) * 4096 + ko * 512 + (qd * 16 + (j & 15)) * 8 + jj;
    *(half4_t*)(swz + off_h) = h;
    if (j == 0) {
        for (int b = lane; b < kM; b += 64) hist[b] = 0u;
        if (lane == 0) loss[0] = 0.0f;
    }
}

// ---------------- main: 2 A-sets/wave, codebook in 8 LDS stages, argmax + gather + loss + hist ------
__global__ __launch_bounds__(128, 2) void vq_main(
    const float* __restrict__ x, const float* __restrict__ emb,
    const _Float16* __restrict__ bswz, const float* __restrict__ bias,
    unsigned int* __restrict__ hist, float* __restrict__ loss_accum,
    float* __restrict__ out) {
    __shared__ _Float16 bb[64 * kD];        // 32768 B: one 64-code stage in fragment order
    __shared__ float lbias[kM];             // 2048 B
    __shared__ unsigned int lhist[kM];      // 2048 B
    __shared__ int lidx[kBM];               // 256 B
    __shared__ float lred[2];

    const int t = threadIdx.x;              // 0..127, 2 waves
    const int row0 = blockIdx.x * kBM;
    const int wave = t >> 6;
    const int lane = t & 63;
    const int qd = lane >> 4;               // quad 0..3
    const int ln = lane & 15;

    #pragma unroll
    for (int b = t; b < kM; b += 128) { lhist[b] = 0u; lbias[b] = bias[b]; }

    // Two A-fragment sets, loaded once: set s covers rows wave*32 + s*16 + {0..15}
    // A[m=ln][k=ko*32+qd*8+j], fp32->fp16
    half8_t a[2][8];
    #pragma unroll
    for (int s = 0; s < 2; ++s) {
        const float* xr = x + (size_t)(row0 + wave * 32 + s * 16 + ln) * kD + qd * 8;
        #pragma unroll
        for (int ko = 0; ko < 8; ++ko) {
            const float4 v0 = *(const float4*)(xr + ko * 32);
            const float4 v1 = *(const float4*)(xr + ko * 32 + 4);
            half8_t h;
            h[0] = (_Float16)v0.x; h[1] = (_Float16)v0.y;
            h[2] = (_Float16)v0.z; h[3] = (_Float16)v0.w;
            h[4] = (_Float16)v1.x; h[5] = (_Float16)v1.y;
            h[6] = (_Float16)v1.z; h[7] = (_Float16)v1.w;
            a[s][ko] = h;
        }
    }

    // argmax over 512 codes in 8 stages of 64; score = x.e_norm - 0.5*||e_norm||^2 (bias in acc init)
    float bv[2][4] = {{-1e30f, -1e30f, -1e30f, -1e30f}, {-1e30f, -1e30f, -1e30f, -1e30f}};
    int bi[2][4] = {{0, 0, 0, 0}, {0, 0, 0, 0}};
    #pragma unroll 1
    for (int st = 0; st < 8; ++st) {
        __syncthreads();   // prior stage's ds_reads done (st=0: covers lhist/lbias init)
        // stage 32 KB (codes 64*st..64*st+63): 128 thr x 16 chunks x 16 B, direct-to-LDS
        {
            const _Float16* src = bswz + (size_t)st * 16384 + wave * 512 + lane * 8;
            _Float16* dst = bb + wave * 512 + lane * 8;
            #pragma unroll
            for (int i = 0; i < 16; ++i)
                __builtin_amdgcn_global_load_lds((gas_t)(const void*)(src + i * 1024),
                                                 (las_t)(void*)(dst + i * 1024), 16, 0, 0);
        }
        __syncthreads();
        #pragma unroll
        for (int sg = 0; sg < 4; ++sg) {
            const int c = st * 64 + sg * 16 + ln;
            const float bbias = lbias[c];
            f32x4 acc0 = {-bbias, -bbias, -bbias, -bbias};
            f32x4 acc1 = {-bbias, -bbias, -bbias, -bbias};
            const half8_t* bp = (const half8_t*)bb + sg * 512 + lane;
            #pragma unroll
            for (int ko = 0; ko < 8; ++ko) {
                const half8_t bf = bp[ko * 64];   // one ds_read_b128 feeds TWO MFMAs
                acc0 = __builtin_amdgcn_mfma_f32_16x16x32_f16(a[0][ko], bf, acc0, 0, 0, 0);
                acc1 = __builtin_amdgcn_mfma_f32_16x16x32_f16(a[1][ko], bf, acc1, 0, 0, 0);
            }
            #pragma unroll
            for (int r = 0; r < 4; ++r) {         // D[m][n]: n=ln, m=qd*4+r
                if (acc0[r] > bv[0][r]) { bv[0][r] = acc0[r]; bi[0][r] = c; }
                if (acc1[r] > bv[1][r]) { bv[1][r] = acc1[r]; bi[1][r] = c; }
            }
        }
    }

    // reduce over the 16 lanes of each quad (same rows, different code subsets)
    #pragma unroll
    for (int s = 0; s < 2; ++s) {
        #pragma unroll
        for (int r = 0; r < 4; ++r) {
            #pragma unroll
            for (int off = 1; off < 16; off <<= 1) {
                const float ov = __shfl_xor(bv[s][r], off);
                const int oi = __shfl_xor(bi[s][r], off);
                if (ov > bv[s][r] || (ov == bv[s][r] && oi < bi[s][r])) { bv[s][r] = ov; bi[s][r] = oi; }
            }
            if (ln == 0) {
                const int row = wave * 32 + s * 16 + qd * 4 + r;
                lidx[row] = bi[s][r];
                atomicAdd(&lhist[bi[s][r]], 1u);
            }
        }
    }
    __syncthreads();

    // epilogue: x re-read coalesced (L2-hot), gather raw codebook row (wave-broadcast 1 KB),
    // write quantized_, accumulate loss
    float lsum = 0.0f;
    {
        const float* xg = x + (size_t)row0 * kD;
        float* og = out + (size_t)row0 * kD;
        #pragma unroll 8
        for (int i = 0; i < 32; ++i) {
            const int g = t * 4 + i * 512;
            const int r = g >> 8;
            const float4 xv = *(const float4*)(xg + g);
            const int idx = lidx[r];
            const float4 q = *(const float4*)(emb + (size_t)idx * kD + (g & 255));
            const float d0 = xv.x - q.x, d1 = xv.y - q.y, d2 = xv.z - q.z, d3 = xv.w - q.w;
            lsum += d0 * d0 + d1 * d1 + d2 * d2 + d3 * d3;
            float4 o;  // ((x + (q-x)) + q) / 2
            o.x = ((xv.x + (q.x - xv.x)) + q.x) * 0.5f;
            o.y = ((xv.y + (q.y - xv.y)) + q.y) * 0.5f;
            o.z = ((xv.z + (q.z - xv.z)) + q.z) * 0.5f;
            o.w = ((xv.w + (q.w - xv.w)) + q.w) * 0.5f;
            *(float4*)&og[g] = o;
        }
    }
    #pragma unroll
    for (int off = 32; off > 0; off >>= 1) lsum += __shfl_xor(lsum, off);
    if (lane == 0) lred[wave] = lsum;
    __syncthreads();
    if (t == 0) atomicAdd(loss_accum, lred[0] + lred[1]);

    // flush histogram (skip zero bins)
    #pragma unroll
    for (int b = t; b < kM; b += 128) {
        const unsigned int h = lhist[b];
        if (h) atomicAdd(&hist[b], h);
    }
}

// ---------------- final: scalars ----------------
__global__ void vq_final(const unsigned int* __restrict__ hist,
                         const float* __restrict__ loss_accum,
                         float* __restrict__ out) {
    const int t = threadIdx.x;  // 256 threads
    __shared__ float sr[4];
    float s = 0.0f;
    for (int b = t; b < kM; b += 256) {
        const float p = (float)hist[b] * (1.0f / 65536.0f);
        s += p * logf(p + 1e-10f);
    }
    #pragma unroll
    for (int off = 32; off > 0; off >>= 1) s += __shfl_xor(s, off);
    if ((t & 63) == 0) sr[t >> 6] = s;
    __syncthreads();
    if (t == 0) {
        const float tot = sr[0] + sr[1] + sr[2] + sr[3];
        out[16777217] = expf(-tot);                           // perplexity
        out[16777216] = loss_accum[0] * (1.0f / 16777216.0f); // commitment loss
    }
}

extern "C" void kernel_launch(void* const* d_in, const int* in_sizes, int n_in,
                              void* d_out, int out_size, void* d_ws, size_t ws_size,
                              hipStream_t stream) {
    const float* x = (const float*)d_in[0];     // (16,4096,256) fp32
    const float* emb = (const float*)d_in[1];   // (512,256) fp32
    char* ws = (char*)d_ws;
    _Float16* bswz = (_Float16*)ws;                           // 512*256*2 = 262144 B
    float* bias = (float*)(ws + 262144);                      // 2048 B
    unsigned int* hist = (unsigned int*)(ws + 262144 + 2048); // 2048 B
    float* loss = (float*)(ws + 262144 + 4096);               // 4 B
    float* out = (float*)d_out;

    vq_prep<<<kM, 64, 0, stream>>>(emb, bswz, bias, hist, loss);
    vq_main<<<kRows / kBM, 128, 0, stream>>>(x, emb, bswz, bias, hist, loss, out);
    vq_final<<<1, 256, 0, stream>>>(hist, loss, out);
}

// Round 6
// 142.900 us; speedup vs baseline: 1.0346x; 1.0346x over previous
//
#include <hip/hip_runtime.h>
#include <hip/hip_bf16.h>

// VQ-VAE quantization forward for MI355X (gfx950).
// outputs (concat in d_out, fp32): quantized_ [16*4096*256], commitment_loss [1], perplexity [1]
//
// R6: 512 blocks x 256 thr (4 waves x 32 rows = 128 rows/block). Each wave holds TWO
// resident A-fragment sets so one B ds_read_b128 feeds 2 MFMAs. Codebook visits LDS in
// 8 stages of 64 codes, DOUBLE-BUFFERED (2x32KB) with CK-style "s_waitcnt vmcnt(8);
// s_barrier" so the prefetch stays in flight across the barrier (no vmcnt(0) drain).

typedef _Float16 half8_t __attribute__((ext_vector_type(8)));
typedef _Float16 half4_t __attribute__((ext_vector_type(4)));
typedef float f32x4 __attribute__((ext_vector_type(4)));

static constexpr int kRows = 65536;   // N*T
static constexpr int kD = 256;
static constexpr int kM = 512;
static constexpr int kBM = 128;       // rows per block

typedef const unsigned int __attribute__((address_space(1)))* gas_t;
typedef unsigned int __attribute__((address_space(3)))* las_t;

// ---------------- prep: normalize codebook -> fp16 in MFMA B-fragment order, bias, zero hist/loss --------
// swz layout (halves): [group g=c>>4][ko=k>>5][lane = qd*16 + (c&15)][j = k&7], qd=(k>>3)&3.
// A wave's read at lane*16B yields B[k=ko*32+qd*8+j][n=g*16+ln] as mfma_f32_16x16x32_f16 wants.
__global__ void vq_prep(const float* __restrict__ emb, _Float16* __restrict__ swz,
                        float* __restrict__ bias, unsigned int* __restrict__ hist,
                        float* __restrict__ loss) {
    const int j = blockIdx.x;       // code row, 512 blocks
    const int lane = threadIdx.x;   // 64 threads = 1 wave
    float4 v = ((const float4*)(emb + j * kD))[lane];
    float ss = v.x * v.x + v.y * v.y + v.z * v.z + v.w * v.w;
    #pragma unroll
    for (int off = 32; off > 0; off >>= 1) ss += __shfl_xor(ss, off);
    const float scale = 1.0f / (sqrtf(ss) + 1e-4f);
    if (lane == 0) bias[j] = 0.5f * ss * scale * scale;
    half4_t h;
    h[0] = (_Float16)(v.x * scale);
    h[1] = (_Float16)(v.y * scale);
    h[2] = (_Float16)(v.z * scale);
    h[3] = (_Float16)(v.w * scale);
    const int k0 = lane * 4;        // this lane covers k0..k0+3 (within one 8-half j-chunk)
    const int ko = k0 >> 5;
    const int qd = (k0 >> 3) & 3;
    const int jj = k0 & 7;          // 0 or 4
    const int off_h = (j >> 4) * 4096 + ko * 512 + (qd * 16 + (j & 15)) * 8 + jj;
    *(half4_t*)(swz + off_h) = h;
    if (j == 0) {
        for (int b = lane; b < kM; b += 64) hist[b] = 0u;
        if (lane == 0) loss[0] = 0.0f;
    }
}

// ---------------- main: 2 A-sets/wave, dbuf codebook stages, argmax + gather + loss + hist ------
__global__ __launch_bounds__(256, 2) void vq_main(
    const float* __restrict__ x, const float* __restrict__ emb,
    const _Float16* __restrict__ bswz, const float* __restrict__ bias,
    unsigned int* __restrict__ hist, float* __restrict__ loss_accum,
    float* __restrict__ out) {
    __shared__ _Float16 bb[2][64 * kD];     // 2 x 32768 B: double-buffered 64-code stages
    __shared__ float lbias[kM];             // 2048 B
    __shared__ unsigned int lhist[kM];      // 2048 B
    __shared__ int lidx[kBM];               // 512 B
    __shared__ float lred[4];

    const int t = threadIdx.x;              // 0..255, 4 waves
    const int row0 = blockIdx.x * kBM;
    const int wave = t >> 6;
    const int lane = t & 63;
    const int qd = lane >> 4;               // quad 0..3
    const int ln = lane & 15;

    lhist[t] = 0u;          lhist[t + 256] = 0u;
    lbias[t] = bias[t];     lbias[t + 256] = bias[t + 256];

    // Two A-fragment sets, loaded once: set s covers rows wave*32 + s*16 + {0..15}
    // A[m=ln][k=ko*32+qd*8+j], fp32->fp16
    half8_t a[2][8];
    #pragma unroll
    for (int s = 0; s < 2; ++s) {
        const float* xr = x + (size_t)(row0 + wave * 32 + s * 16 + ln) * kD + qd * 8;
        #pragma unroll
        for (int ko = 0; ko < 8; ++ko) {
            const float4 v0 = *(const float4*)(xr + ko * 32);
            const float4 v1 = *(const float4*)(xr + ko * 32 + 4);
            half8_t h;
            h[0] = (_Float16)v0.x; h[1] = (_Float16)v0.y;
            h[2] = (_Float16)v0.z; h[3] = (_Float16)v0.w;
            h[4] = (_Float16)v1.x; h[5] = (_Float16)v1.y;
            h[6] = (_Float16)v1.z; h[7] = (_Float16)v1.w;
            a[s][ko] = h;
        }
    }

    // stage loader: 32 KB (codes 64*st..64*st+63), 256 thr x 8 chunks x 16 B, direct-to-LDS.
    // per-instr dst = wave-uniform base + lane*16B (required by global_load_lds).
    auto stage_load = [&](int st, int buf) {
        const _Float16* src = bswz + (size_t)st * 16384 + t * 8;
        _Float16* dst = &bb[buf][0] + t * 8;
        #pragma unroll
        for (int i = 0; i < 8; ++i)
            __builtin_amdgcn_global_load_lds((gas_t)(const void*)(src + i * 2048),
                                             (las_t)(void*)(dst + i * 2048), 16, 0, 0);
    };

    stage_load(0, 0);   // prologue

    // argmax over 512 codes in 8 stages of 64; score = x.e_norm - 0.5*||e_norm||^2 (bias in acc init)
    float bv[2][4] = {{-1e30f, -1e30f, -1e30f, -1e30f}, {-1e30f, -1e30f, -1e30f, -1e30f}};
    int bi[2][4] = {{0, 0, 0, 0}, {0, 0, 0, 0}};
    #pragma unroll 1
    for (int st = 0; st < 8; ++st) {
        if (st < 7) stage_load(st + 1, (st + 1) & 1);   // prefetch into idle buffer
        // wait only the OLDER 8 loads (stage st); prefetch stays in flight across barrier
        if (st == 0)      __asm__ __volatile__("s_waitcnt vmcnt(8) lgkmcnt(0)\ns_barrier" ::: "memory");
        else if (st < 7)  __asm__ __volatile__("s_waitcnt vmcnt(8)\ns_barrier" ::: "memory");
        else              __asm__ __volatile__("s_waitcnt vmcnt(0)\ns_barrier" ::: "memory");

        const _Float16* bbase = &bb[st & 1][0];
        #pragma unroll
        for (int sg = 0; sg < 4; ++sg) {
            const int c = st * 64 + sg * 16 + ln;
            const float bbias = lbias[c];
            f32x4 acc0 = {-bbias, -bbias, -bbias, -bbias};
            f32x4 acc1 = {-bbias, -bbias, -bbias, -bbias};
            const half8_t* bp = (const half8_t*)bbase + sg * 512 + lane;
            #pragma unroll
            for (int ko = 0; ko < 8; ++ko) {
                const half8_t bf = bp[ko * 64];   // one ds_read_b128 feeds TWO MFMAs
                acc0 = __builtin_amdgcn_mfma_f32_16x16x32_f16(a[0][ko], bf, acc0, 0, 0, 0);
                acc1 = __builtin_amdgcn_mfma_f32_16x16x32_f16(a[1][ko], bf, acc1, 0, 0, 0);
            }
            #pragma unroll
            for (int r = 0; r < 4; ++r) {         // D[m][n]: n=ln, m=qd*4+r
                if (acc0[r] > bv[0][r]) { bv[0][r] = acc0[r]; bi[0][r] = c; }
                if (acc1[r] > bv[1][r]) { bv[1][r] = acc1[r]; bi[1][r] = c; }
            }
        }
        // readers of bb[st&1] done before stage st+2 overwrites it (no memory drain needed:
        // ds_read results already lgkm-waited before their MFMA use)
        if (st < 7) __asm__ __volatile__("s_barrier" ::: "memory");
    }

    // reduce over the 16 lanes of each quad (same rows, different code subsets)
    #pragma unroll
    for (int s = 0; s < 2; ++s) {
        #pragma unroll
        for (int r = 0; r < 4; ++r) {
            #pragma unroll
            for (int off = 1; off < 16; off <<= 1) {
                const float ov = __shfl_xor(bv[s][r], off);
                const int oi = __shfl_xor(bi[s][r], off);
                if (ov > bv[s][r] || (ov == bv[s][r] && oi < bi[s][r])) { bv[s][r] = ov; bi[s][r] = oi; }
            }
            if (ln == 0) {
                const int row = wave * 32 + s * 16 + qd * 4 + r;
                lidx[row] = bi[s][r];
                atomicAdd(&lhist[bi[s][r]], 1u);
            }
        }
    }
    __syncthreads();

    // epilogue: x re-read coalesced (L2/L3-hot), gather raw codebook row (wave-broadcast 1 KB),
    // write quantized_, accumulate loss
    float lsum = 0.0f;
    {
        const float* xg = x + (size_t)row0 * kD;
        float* og = out + (size_t)row0 * kD;
        #pragma unroll 8
        for (int i = 0; i < 32; ++i) {
            const int g = t * 4 + i * 1024;
            const int r = g >> 8;
            const float4 xv = *(const float4*)(xg + g);
            const int idx = lidx[r];
            const float4 q = *(const float4*)(emb + (size_t)idx * kD + (g & 255));
            const float d0 = xv.x - q.x, d1 = xv.y - q.y, d2 = xv.z - q.z, d3 = xv.w - q.w;
            lsum += d0 * d0 + d1 * d1 + d2 * d2 + d3 * d3;
            float4 o;  // ((x + (q-x)) + q) / 2
            o.x = ((xv.x + (q.x - xv.x)) + q.x) * 0.5f;
            o.y = ((xv.y + (q.y - xv.y)) + q.y) * 0.5f;
            o.z = ((xv.z + (q.z - xv.z)) + q.z) * 0.5f;
            o.w = ((xv.w + (q.w - xv.w)) + q.w) * 0.5f;
            *(float4*)&og[g] = o;
        }
    }
    #pragma unroll
    for (int off = 32; off > 0; off >>= 1) lsum += __shfl_xor(lsum, off);
    if (lane == 0) lred[wave] = lsum;
    __syncthreads();
    if (t == 0) atomicAdd(loss_accum, lred[0] + lred[1] + lred[2] + lred[3]);

    // flush histogram (skip zero bins)
    const unsigned int h0 = lhist[t];
    if (h0) atomicAdd(&hist[t], h0);
    const unsigned int h1 = lhist[t + 256];
    if (h1) atomicAdd(&hist[t + 256], h1);
}

// ---------------- final: scalars ----------------
__global__ void vq_final(const unsigned int* __restrict__ hist,
                         const float* __restrict__ loss_accum,
                         float* __restrict__ out) {
    const int t = threadIdx.x;  // 256 threads
    __shared__ float sr[4];
    float s = 0.0f;
    for (int b = t; b < kM; b += 256) {
        const float p = (float)hist[b] * (1.0f / 65536.0f);
        s += p * logf(p + 1e-10f);
    }
    #pragma unroll
    for (int off = 32; off > 0; off >>= 1) s += __shfl_xor(s, off);
    if ((t & 63) == 0) sr[t >> 6] = s;
    __syncthreads();
    if (t == 0) {
        const float tot = sr[0] + sr[1] + sr[2] + sr[3];
        out[16777217] = expf(-tot);                           // perplexity
        out[16777216] = loss_accum[0] * (1.0f / 16777216.0f); // commitment loss
    }
}

extern "C" void kernel_launch(void* const* d_in, const int* in_sizes, int n_in,
                              void* d_out, int out_size, void* d_ws, size_t ws_size,
                              hipStream_t stream) {
    const float* x = (const float*)d_in[0];     // (16,4096,256) fp32
    const float* emb = (const float*)d_in[1];   // (512,256) fp32
    char* ws = (char*)d_ws;
    _Float16* bswz = (_Float16*)ws;                           // 512*256*2 = 262144 B
    float* bias = (float*)(ws + 262144);                      // 2048 B
    unsigned int* hist = (unsigned int*)(ws + 262144 + 2048); // 2048 B
    float* loss = (float*)(ws + 262144 + 4096);               // 4 B
    float* out = (float*)d_out;

    vq_prep<<<kM, 64, 0, stream>>>(emb, bswz, bias, hist, loss);
    vq_main<<<kRows / kBM, 256, 0, stream>>>(x, emb, bswz, bias, hist, loss, out);
    vq_final<<<1, 256, 0, stream>>>(hist, loss, out);
}